// Round 1
// baseline (1339.991 us; speedup 1.0000x reference)
//
#include <hip/hip_runtime.h>
#include <math.h>

#define N_USERS 100000
#define N_ITEMS 50000
#define NE      2000000
#define NB      100000
#define H       64
#define BN_EPS  1e-5f

static __device__ __forceinline__ int rfl(int x) { return __builtin_amdgcn_readfirstlane(x); }

// ---------------- projection: Y[N,64] = X[N,K] @ W[K,64] + b ----------------
// 4 waves/block split K; W k-slice columns live in VGPRs (lane = out channel);
// X row elements are wave-uniform -> scalar loads; LDS only for 4-way reduce.
template<int K>
__global__ __launch_bounds__(256) void proj_kernel(
    const float* __restrict__ X, const float* __restrict__ W,
    const float* __restrict__ bias, float* __restrict__ Y, int nrows) {
  constexpr int SL = K / 4;
  const int lane = threadIdx.x & 63;
  const int wid  = rfl((int)(threadIdx.x >> 6));
  const int k0   = wid * SL;
  float w[SL];
#pragma unroll
  for (int k = 0; k < SL; k++) w[k] = W[(k0 + k) * H + lane];
  const float bv = bias[lane];
  __shared__ float part[4][64];
  for (int r = blockIdx.x; r < nrows; r += gridDim.x) {
    const float* xr = X + (size_t)r * K + k0;
    float acc = 0.f;
#pragma unroll
    for (int k = 0; k < SL; k++) acc = fmaf(xr[k], w[k], acc);
    part[wid][lane] = acc;
    __syncthreads();
    if (wid == 0) {
      Y[(size_t)r * H + lane] =
          part[0][lane] + part[1][lane] + part[2][lane] + part[3][lane] + bv;
    }
    __syncthreads();
  }
}

// ---------------- CSR build ----------------
__global__ __launch_bounds__(256) void hist_kernel(
    const int* __restrict__ src, const int* __restrict__ dst,
    int* __restrict__ cntU, int* __restrict__ cntI) {
  int e = blockIdx.x * blockDim.x + threadIdx.x;
  const int stride = gridDim.x * blockDim.x;
  for (; e < NE; e += stride) {
    atomicAdd(&cntU[src[e]], 1);
    atomicAdd(&cntI[dst[e]], 1);
  }
}

// single-block scan: 4 elems/thread, wave shfl-scan, LDS combine of 16 wave totals
__global__ __launch_bounds__(1024) void scan_kernel(
    const int* __restrict__ cnt, int* __restrict__ row, int* __restrict__ cur, int n) {
  __shared__ int wtot[16];
  __shared__ int carry_s;
  const int tid = threadIdx.x;
  const int lane = tid & 63, wv = tid >> 6;
  if (tid == 0) { carry_s = 0; row[0] = 0; }
  __syncthreads();
  for (int base = 0; base < n; base += 4096) {
    const int i0 = base + tid * 4;
    const int v0 = (i0 + 0 < n) ? cnt[i0 + 0] : 0;
    const int v1 = (i0 + 1 < n) ? cnt[i0 + 1] : 0;
    const int v2 = (i0 + 2 < n) ? cnt[i0 + 2] : 0;
    const int v3 = (i0 + 3 < n) ? cnt[i0 + 3] : 0;
    const int s0 = v0, s1 = s0 + v1, s2 = s1 + v2, s3 = s2 + v3;
    int x = s3;
#pragma unroll
    for (int off = 1; off < 64; off <<= 1) {
      int y = __shfl_up(x, off);
      if (lane >= off) x += y;
    }
    if (lane == 63) wtot[wv] = x;
    __syncthreads();
    int woff = 0;
#pragma unroll
    for (int k = 0; k < 16; k++) woff += (k < wv) ? wtot[k] : 0;
    const int thr_excl = (x - s3) + woff + carry_s;
    if (i0 + 0 < n) { cur[i0 + 0] = thr_excl;      row[i0 + 1] = thr_excl + s0; }
    if (i0 + 1 < n) { cur[i0 + 1] = thr_excl + s0; row[i0 + 2] = thr_excl + s1; }
    if (i0 + 2 < n) { cur[i0 + 2] = thr_excl + s1; row[i0 + 3] = thr_excl + s2; }
    if (i0 + 3 < n) { cur[i0 + 3] = thr_excl + s2; row[i0 + 4] = thr_excl + s3; }
    __syncthreads();
    if (tid == 1023) carry_s = thr_excl + s3;
    __syncthreads();
  }
}

__global__ __launch_bounds__(256) void scatter_kernel(
    const int* __restrict__ src, const int* __restrict__ dst,
    int* __restrict__ curU, int* __restrict__ curI,
    int* __restrict__ adjU, int* __restrict__ adjI) {
  int e = blockIdx.x * blockDim.x + threadIdx.x;
  const int stride = gridDim.x * blockDim.x;
  for (; e < NE; e += stride) {
    const int u = src[e], it = dst[e];
    const int pu = atomicAdd(&curU[u], 1);
    adjU[pu] = it;
    const int pi = atomicAdd(&curI[it], 1);
    adjI[pi] = u;
  }
}

// ---------------- aggregations: one wave per segment, lane = channel ----------------
__global__ __launch_bounds__(256) void agg_max_kernel(
    const float* __restrict__ feat, const int* __restrict__ rowptr,
    const int* __restrict__ adj, float* __restrict__ out, int nseg) {
  const int lane = threadIdx.x & 63;
  const int wid  = rfl((int)(threadIdx.x >> 6));
  for (int s = blockIdx.x * 4 + wid; s < nseg; s += gridDim.x * 4) {
    const int beg = rowptr[s], end = rowptr[s + 1];
    float m0 = -INFINITY, m1 = -INFINITY, m2 = -INFINITY, m3 = -INFINITY;
    int j = beg;
    for (; j + 4 <= end; j += 4) {
      const int n0 = adj[j], n1 = adj[j + 1], n2 = adj[j + 2], n3 = adj[j + 3];
      m0 = fmaxf(m0, feat[(size_t)n0 * H + lane]);
      m1 = fmaxf(m1, feat[(size_t)n1 * H + lane]);
      m2 = fmaxf(m2, feat[(size_t)n2 * H + lane]);
      m3 = fmaxf(m3, feat[(size_t)n3 * H + lane]);
    }
    for (; j < end; j++) m0 = fmaxf(m0, feat[(size_t)adj[j] * H + lane]);
    const float m = fmaxf(fmaxf(m0, m1), fmaxf(m2, m3));
    out[(size_t)s * H + lane] = (end > beg) ? m : 0.f;  // empty segment -> 0 (PyG)
  }
}

__global__ __launch_bounds__(256) void agg_mean_kernel(
    const float* __restrict__ feat, const int* __restrict__ rowptr,
    const int* __restrict__ adj, float* __restrict__ out, int nseg) {
  const int lane = threadIdx.x & 63;
  const int wid  = rfl((int)(threadIdx.x >> 6));
  for (int s = blockIdx.x * 4 + wid; s < nseg; s += gridDim.x * 4) {
    const int beg = rowptr[s], end = rowptr[s + 1];
    float a0 = 0.f, a1 = 0.f, a2 = 0.f, a3 = 0.f;
    int j = beg;
    for (; j + 4 <= end; j += 4) {
      const int n0 = adj[j], n1 = adj[j + 1], n2 = adj[j + 2], n3 = adj[j + 3];
      a0 += feat[(size_t)n0 * H + lane];
      a1 += feat[(size_t)n1 * H + lane];
      a2 += feat[(size_t)n2 * H + lane];
      a3 += feat[(size_t)n3 * H + lane];
    }
    for (; j < end; j++) a0 += feat[(size_t)adj[j] * H + lane];
    const float inv = 1.f / (float)((end - beg) > 1 ? (end - beg) : 1);
    out[(size_t)s * H + lane] = ((a0 + a1) + (a2 + a3)) * inv;
  }
}

// ---------------- fused conv: Y = relu(BN(AGG@Wl + bl + XS@Wr)) ----------------
// one wave/row; both 64-wide W columns in VGPRs; row activations wave-uniform (s_load)
__global__ __launch_bounds__(256) void conv_kernel(
    const float* __restrict__ AGG, const float* __restrict__ XS,
    const float* __restrict__ Wl, const float* __restrict__ bl,
    const float* __restrict__ Wr, const float* __restrict__ gm,
    const float* __restrict__ bt, const float* __restrict__ mu,
    const float* __restrict__ vr, float* __restrict__ Y, int nrows) {
  const int lane = threadIdx.x & 63;
  const int wid  = rfl((int)(threadIdx.x >> 6));
  float wl[64], wr[64];
#pragma unroll
  for (int k = 0; k < 64; k++) wl[k] = Wl[k * 64 + lane];
#pragma unroll
  for (int k = 0; k < 64; k++) wr[k] = Wr[k * 64 + lane];
  const float s = gm[lane] * rsqrtf(vr[lane] + BN_EPS);
  const float C = (bl[lane] - mu[lane]) * s + bt[lane];
  for (int r = blockIdx.x * 4 + wid; r < nrows; r += gridDim.x * 4) {
    const float* a = AGG + (size_t)r * 64;
    const float* x = XS + (size_t)r * 64;
    float acc = 0.f;
#pragma unroll
    for (int k = 0; k < 64; k++) acc = fmaf(a[k], wl[k], acc);
#pragma unroll
    for (int k = 0; k < 64; k++) acc = fmaf(x[k], wr[k], acc);
    Y[(size_t)r * 64 + lane] = fmaxf(fmaf(acc, s, C), 0.f);
  }
}

// ---------------- head: out[b,:4] = relu([uh|ih] @ fc1 + b1) @ fc2 + b2 ----------------
__global__ __launch_bounds__(256) void head_kernel(
    const float* __restrict__ ux, const float* __restrict__ ix,
    const int* __restrict__ eliU, const int* __restrict__ eliI,
    const float* __restrict__ W1, const float* __restrict__ b1,
    const float* __restrict__ W2, const float* __restrict__ b2,
    float* __restrict__ out) {
  const int lane = threadIdx.x & 63;
  const int wid  = rfl((int)(threadIdx.x >> 6));
  float w1[128];
#pragma unroll
  for (int k = 0; k < 128; k++) w1[k] = W1[k * 64 + lane];
  const float b1v = b1[lane];
  const float w2a = W2[lane * 4 + 0], w2b = W2[lane * 4 + 1];
  const float w2c = W2[lane * 4 + 2], w2d = W2[lane * 4 + 3];
  const float c0 = b2[0], c1 = b2[1], c2 = b2[2], c3 = b2[3];
  for (int b = blockIdx.x * 4 + wid; b < NB; b += gridDim.x * 4) {
    const int u = eliU[b], it = eliI[b];
    const float* xu = ux + (size_t)u * 64;
    const float* xi = ix + (size_t)it * 64;
    float acc = b1v;
#pragma unroll
    for (int k = 0; k < 64; k++) acc = fmaf(xu[k], w1[k], acc);
#pragma unroll
    for (int k = 0; k < 64; k++) acc = fmaf(xi[k], w1[64 + k], acc);
    const float h = fmaxf(acc, 0.f);
    float o0 = h * w2a, o1 = h * w2b, o2 = h * w2c, o3 = h * w2d;
#pragma unroll
    for (int off = 32; off; off >>= 1) {
      o0 += __shfl_down(o0, off);
      o1 += __shfl_down(o1, off);
      o2 += __shfl_down(o2, off);
      o3 += __shfl_down(o3, off);
    }
    if (lane == 0) {
      float4 o = { o0 + c0, o1 + c1, o2 + c2, o3 + c3 };
      *reinterpret_cast<float4*>(out + (size_t)b * 4) = o;
    }
  }
}

// ---------------- launch ----------------
extern "C" void kernel_launch(void* const* d_in, const int* in_sizes, int n_in,
                              void* d_out, int out_size, void* d_ws, size_t ws_size,
                              hipStream_t stream) {
  const float* userF = (const float*)d_in[0];
  const float* itemF = (const float*)d_in[1];
  const int*   src   = (const int*)d_in[2];
  const int*   dst   = src + NE;
  const int*   eliU  = (const int*)d_in[3];
  const int*   eliI  = eliU + NB;
  const float* upW = (const float*)d_in[4],  *upb = (const float*)d_in[5];
  const float* ipW = (const float*)d_in[6],  *ipb = (const float*)d_in[7];
  const float* ulW = (const float*)d_in[8],  *ulb = (const float*)d_in[9];
  const float* urW = (const float*)d_in[10];
  const float* ilW = (const float*)d_in[11], *ilb = (const float*)d_in[12];
  const float* irW = (const float*)d_in[13];
  const float* ug  = (const float*)d_in[14], *ube = (const float*)d_in[15];
  const float* um  = (const float*)d_in[16], *uv  = (const float*)d_in[17];
  const float* ig  = (const float*)d_in[18], *ibe = (const float*)d_in[19];
  const float* im  = (const float*)d_in[20], *iv  = (const float*)d_in[21];
  const float* f1W = (const float*)d_in[22], *f1b = (const float*)d_in[23];
  const float* f2W = (const float*)d_in[24], *f2b = (const float*)d_in[25];
  float* outp = (float*)d_out;

  char* p = (char*)d_ws;
  auto alloc = [&](size_t bytes) {
    char* r = p;
    p += (bytes + 255) & ~(size_t)255;
    return r;
  };
  float* ux0  = (float*)alloc((size_t)N_USERS * H * 4);
  float* ux1  = (float*)alloc((size_t)N_USERS * H * 4);
  float* ix0  = (float*)alloc((size_t)N_ITEMS * H * 4);
  float* ix1  = (float*)alloc((size_t)N_ITEMS * H * 4);
  float* agU  = (float*)alloc((size_t)N_USERS * H * 4);
  float* agI  = (float*)alloc((size_t)N_ITEMS * H * 4);
  int*   rowU = (int*)alloc((size_t)(N_USERS + 1) * 4);
  int*   rowI = (int*)alloc((size_t)(N_ITEMS + 1) * 4);
  int*   curU = (int*)alloc((size_t)N_USERS * 4);
  int*   curI = (int*)alloc((size_t)N_ITEMS * 4);
  int*   cntUI = (int*)alloc((size_t)(N_USERS + N_ITEMS) * 4);
  int*   cntU = cntUI;
  int*   cntI = cntUI + N_USERS;
  int*   adjU = (int*)alloc((size_t)NE * 4);
  int*   adjI = (int*)alloc((size_t)NE * 4);

  hipMemsetAsync(cntUI, 0, (size_t)(N_USERS + N_ITEMS) * 4, stream);

  const int G = 2048, T = 256;
  proj_kernel<256><<<G, T, 0, stream>>>(userF, upW, upb, ux0, N_USERS);
  proj_kernel<128><<<G, T, 0, stream>>>(itemF, ipW, ipb, ix0, N_ITEMS);
  hist_kernel<<<G, T, 0, stream>>>(src, dst, cntU, cntI);
  scan_kernel<<<1, 1024, 0, stream>>>(cntU, rowU, curU, N_USERS);
  scan_kernel<<<1, 1024, 0, stream>>>(cntI, rowI, curI, N_ITEMS);
  scatter_kernel<<<G, T, 0, stream>>>(src, dst, curU, curI, adjU, adjI);

  const float* uin = ux0;
  const float* iin = ix0;
  float* uout = ux1;
  float* iout = ix1;
  for (int l = 0; l < 2; l++) {
    agg_max_kernel<<<G, T, 0, stream>>>(iin, rowU, adjU, agU, N_USERS);
    conv_kernel<<<G, T, 0, stream>>>(agU, uin, ulW + l * 4096, ulb + l * 64,
                                     urW + l * 4096, ug + l * 64, ube + l * 64,
                                     um + l * 64, uv + l * 64, uout, N_USERS);
    agg_mean_kernel<<<G, T, 0, stream>>>(uin, rowI, adjI, agI, N_ITEMS);
    conv_kernel<<<G, T, 0, stream>>>(agI, iin, ilW + l * 4096, ilb + l * 64,
                                     irW + l * 4096, ig + l * 64, ibe + l * 64,
                                     im + l * 64, iv + l * 64, iout, N_ITEMS);
    const float* t;
    t = uin; uin = uout; uout = (float*)t;
    t = iin; iin = iout; iout = (float*)t;
  }
  head_kernel<<<G, T, 0, stream>>>(uin, iin, eliU, eliI, f1W, f1b, f2W, f2b, outp);
}

// Round 2
// 1143.598 us; speedup vs baseline: 1.1717x; 1.1717x over previous
//
#include <hip/hip_runtime.h>
#include <math.h>

#define N_USERS 100000
#define N_ITEMS 50000
#define NE      2000000
#define NB      100000
#define H       64
#define BN_EPS  1e-5f
#define NXCD    8
#define U_PER_XCD (N_USERS / NXCD)   // 12500
#define I_PER_XCD (N_ITEMS / NXCD)   // 6250

static __device__ __forceinline__ int rfl(int x) { return __builtin_amdgcn_readfirstlane(x); }

// ---------------- projection: Y[N,64] = X[N,K] @ W[K,64] + b ----------------
template<int K>
__global__ __launch_bounds__(256) void proj_kernel(
    const float* __restrict__ X, const float* __restrict__ W,
    const float* __restrict__ bias, float* __restrict__ Y, int nrows) {
  constexpr int SL = K / 4;
  const int lane = threadIdx.x & 63;
  const int wid  = rfl((int)(threadIdx.x >> 6));
  const int k0   = wid * SL;
  float w[SL];
#pragma unroll
  for (int k = 0; k < SL; k++) w[k] = W[(k0 + k) * H + lane];
  const float bv = bias[lane];
  __shared__ float part[4][64];
  for (int r = blockIdx.x; r < nrows; r += gridDim.x) {
    const float* xr = X + (size_t)r * K + k0;
    float acc = 0.f;
#pragma unroll
    for (int k = 0; k < SL; k++) acc = fmaf(xr[k], w[k], acc);
    part[wid][lane] = acc;
    __syncthreads();
    if (wid == 0) {
      Y[(size_t)r * H + lane] =
          part[0][lane] + part[1][lane] + part[2][lane] + part[3][lane] + bv;
    }
    __syncthreads();
  }
}

// ---------------- CSR build (XCD-ownership partitioned) ----------------
// blockIdx%8 -> XCD x owns user range [x*12500,..) and item range [x*6250,..).
// Each XCD's block subset scans ALL edges (L3-served after first touch,
// nontemporal so the stream doesn't evict dirty lines in L2) but only
// updates nodes it owns -> counter/adjacency lines are single-XCD-owned,
// accumulate in that L2, and write back as (mostly) full lines.
__global__ __launch_bounds__(256) void hist_kernel(
    const int* __restrict__ src, const int* __restrict__ dst,
    int* __restrict__ cntU, int* __restrict__ cntI) {
  const int xcd = blockIdx.x & (NXCD - 1);
  const int sub = blockIdx.x >> 3;
  const int nsub = gridDim.x >> 3;
  const int uLo = xcd * U_PER_XCD, uHi = uLo + U_PER_XCD;
  const int iLo = xcd * I_PER_XCD, iHi = iLo + I_PER_XCD;
  int e = sub * blockDim.x + threadIdx.x;
  const int stride = nsub * blockDim.x;
  for (; e < NE; e += stride) {
    const int u  = __builtin_nontemporal_load(&src[e]);
    const int it = __builtin_nontemporal_load(&dst[e]);
    if (u >= uLo && u < uHi)  atomicAdd(&cntU[u], 1);
    if (it >= iLo && it < iHi) atomicAdd(&cntI[it], 1);
  }
}

// single-block scan: 4 elems/thread, wave shfl-scan, LDS combine of 16 wave totals
__global__ __launch_bounds__(1024) void scan_kernel(
    const int* __restrict__ cnt, int* __restrict__ row, int* __restrict__ cur, int n) {
  __shared__ int wtot[16];
  __shared__ int carry_s;
  const int tid = threadIdx.x;
  const int lane = tid & 63, wv = tid >> 6;
  if (tid == 0) { carry_s = 0; row[0] = 0; }
  __syncthreads();
  for (int base = 0; base < n; base += 4096) {
    const int i0 = base + tid * 4;
    const int v0 = (i0 + 0 < n) ? cnt[i0 + 0] : 0;
    const int v1 = (i0 + 1 < n) ? cnt[i0 + 1] : 0;
    const int v2 = (i0 + 2 < n) ? cnt[i0 + 2] : 0;
    const int v3 = (i0 + 3 < n) ? cnt[i0 + 3] : 0;
    const int s0 = v0, s1 = s0 + v1, s2 = s1 + v2, s3 = s2 + v3;
    int x = s3;
#pragma unroll
    for (int off = 1; off < 64; off <<= 1) {
      int y = __shfl_up(x, off);
      if (lane >= off) x += y;
    }
    if (lane == 63) wtot[wv] = x;
    __syncthreads();
    int woff = 0;
#pragma unroll
    for (int k = 0; k < 16; k++) woff += (k < wv) ? wtot[k] : 0;
    const int thr_excl = (x - s3) + woff + carry_s;
    if (i0 + 0 < n) { cur[i0 + 0] = thr_excl;      row[i0 + 1] = thr_excl + s0; }
    if (i0 + 1 < n) { cur[i0 + 1] = thr_excl + s0; row[i0 + 2] = thr_excl + s1; }
    if (i0 + 2 < n) { cur[i0 + 2] = thr_excl + s1; row[i0 + 3] = thr_excl + s2; }
    if (i0 + 3 < n) { cur[i0 + 3] = thr_excl + s2; row[i0 + 4] = thr_excl + s3; }
    __syncthreads();
    if (tid == 1023) carry_s = thr_excl + s3;
    __syncthreads();
  }
}

__global__ __launch_bounds__(256) void scatter_kernel(
    const int* __restrict__ src, const int* __restrict__ dst,
    int* __restrict__ curU, int* __restrict__ curI,
    int* __restrict__ adjU, int* __restrict__ adjI) {
  const int xcd = blockIdx.x & (NXCD - 1);
  const int sub = blockIdx.x >> 3;
  const int nsub = gridDim.x >> 3;
  const int uLo = xcd * U_PER_XCD, uHi = uLo + U_PER_XCD;
  const int iLo = xcd * I_PER_XCD, iHi = iLo + I_PER_XCD;
  int e = sub * blockDim.x + threadIdx.x;
  const int stride = nsub * blockDim.x;
  for (; e < NE; e += stride) {
    const int u  = __builtin_nontemporal_load(&src[e]);
    const int it = __builtin_nontemporal_load(&dst[e]);
    if (u >= uLo && u < uHi) {
      const int pu = atomicAdd(&curU[u], 1);
      adjU[pu] = it;
    }
    if (it >= iLo && it < iHi) {
      const int pi = atomicAdd(&curI[it], 1);
      adjI[pi] = u;
    }
  }
}

// ---------------- aggregations: one wave per segment, lane = channel ----------------
__global__ __launch_bounds__(256) void agg_max_kernel(
    const float* __restrict__ feat, const int* __restrict__ rowptr,
    const int* __restrict__ adj, float* __restrict__ out, int nseg) {
  const int lane = threadIdx.x & 63;
  const int wid  = rfl((int)(threadIdx.x >> 6));
  for (int s = blockIdx.x * 4 + wid; s < nseg; s += gridDim.x * 4) {
    const int beg = rowptr[s], end = rowptr[s + 1];
    float m0 = -INFINITY, m1 = -INFINITY, m2 = -INFINITY, m3 = -INFINITY;
    int j = beg;
    for (; j + 4 <= end; j += 4) {
      const int n0 = adj[j], n1 = adj[j + 1], n2 = adj[j + 2], n3 = adj[j + 3];
      m0 = fmaxf(m0, feat[(size_t)n0 * H + lane]);
      m1 = fmaxf(m1, feat[(size_t)n1 * H + lane]);
      m2 = fmaxf(m2, feat[(size_t)n2 * H + lane]);
      m3 = fmaxf(m3, feat[(size_t)n3 * H + lane]);
    }
    for (; j < end; j++) m0 = fmaxf(m0, feat[(size_t)adj[j] * H + lane]);
    const float m = fmaxf(fmaxf(m0, m1), fmaxf(m2, m3));
    out[(size_t)s * H + lane] = (end > beg) ? m : 0.f;  // empty segment -> 0 (PyG)
  }
}

__global__ __launch_bounds__(256) void agg_mean_kernel(
    const float* __restrict__ feat, const int* __restrict__ rowptr,
    const int* __restrict__ adj, float* __restrict__ out, int nseg) {
  const int lane = threadIdx.x & 63;
  const int wid  = rfl((int)(threadIdx.x >> 6));
  for (int s = blockIdx.x * 4 + wid; s < nseg; s += gridDim.x * 4) {
    const int beg = rowptr[s], end = rowptr[s + 1];
    float a0 = 0.f, a1 = 0.f, a2 = 0.f, a3 = 0.f;
    int j = beg;
    for (; j + 4 <= end; j += 4) {
      const int n0 = adj[j], n1 = adj[j + 1], n2 = adj[j + 2], n3 = adj[j + 3];
      a0 += feat[(size_t)n0 * H + lane];
      a1 += feat[(size_t)n1 * H + lane];
      a2 += feat[(size_t)n2 * H + lane];
      a3 += feat[(size_t)n3 * H + lane];
    }
    for (; j < end; j++) a0 += feat[(size_t)adj[j] * H + lane];
    const float inv = 1.f / (float)((end - beg) > 1 ? (end - beg) : 1);
    out[(size_t)s * H + lane] = ((a0 + a1) + (a2 + a3)) * inv;
  }
}

// ---------------- fused conv: Y = relu(BN(AGG@Wl + bl + XS@Wr)) ----------------
__global__ __launch_bounds__(256) void conv_kernel(
    const float* __restrict__ AGG, const float* __restrict__ XS,
    const float* __restrict__ Wl, const float* __restrict__ bl,
    const float* __restrict__ Wr, const float* __restrict__ gm,
    const float* __restrict__ bt, const float* __restrict__ mu,
    const float* __restrict__ vr, float* __restrict__ Y, int nrows) {
  const int lane = threadIdx.x & 63;
  const int wid  = rfl((int)(threadIdx.x >> 6));
  float wl[64], wr[64];
#pragma unroll
  for (int k = 0; k < 64; k++) wl[k] = Wl[k * 64 + lane];
#pragma unroll
  for (int k = 0; k < 64; k++) wr[k] = Wr[k * 64 + lane];
  const float s = gm[lane] * rsqrtf(vr[lane] + BN_EPS);
  const float C = (bl[lane] - mu[lane]) * s + bt[lane];
  for (int r = blockIdx.x * 4 + wid; r < nrows; r += gridDim.x * 4) {
    const float* a = AGG + (size_t)r * 64;
    const float* x = XS + (size_t)r * 64;
    float acc = 0.f;
#pragma unroll
    for (int k = 0; k < 64; k++) acc = fmaf(a[k], wl[k], acc);
#pragma unroll
    for (int k = 0; k < 64; k++) acc = fmaf(x[k], wr[k], acc);
    Y[(size_t)r * 64 + lane] = fmaxf(fmaf(acc, s, C), 0.f);
  }
}

// ---------------- head ----------------
__global__ __launch_bounds__(256) void head_kernel(
    const float* __restrict__ ux, const float* __restrict__ ix,
    const int* __restrict__ eliU, const int* __restrict__ eliI,
    const float* __restrict__ W1, const float* __restrict__ b1,
    const float* __restrict__ W2, const float* __restrict__ b2,
    float* __restrict__ out) {
  const int lane = threadIdx.x & 63;
  const int wid  = rfl((int)(threadIdx.x >> 6));
  float w1[128];
#pragma unroll
  for (int k = 0; k < 128; k++) w1[k] = W1[k * 64 + lane];
  const float b1v = b1[lane];
  const float w2a = W2[lane * 4 + 0], w2b = W2[lane * 4 + 1];
  const float w2c = W2[lane * 4 + 2], w2d = W2[lane * 4 + 3];
  const float c0 = b2[0], c1 = b2[1], c2 = b2[2], c3 = b2[3];
  for (int b = blockIdx.x * 4 + wid; b < NB; b += gridDim.x * 4) {
    const int u = eliU[b], it = eliI[b];
    const float* xu = ux + (size_t)u * 64;
    const float* xi = ix + (size_t)it * 64;
    float acc = b1v;
#pragma unroll
    for (int k = 0; k < 64; k++) acc = fmaf(xu[k], w1[k], acc);
#pragma unroll
    for (int k = 0; k < 64; k++) acc = fmaf(xi[k], w1[64 + k], acc);
    const float h = fmaxf(acc, 0.f);
    float o0 = h * w2a, o1 = h * w2b, o2 = h * w2c, o3 = h * w2d;
#pragma unroll
    for (int off = 32; off; off >>= 1) {
      o0 += __shfl_down(o0, off);
      o1 += __shfl_down(o1, off);
      o2 += __shfl_down(o2, off);
      o3 += __shfl_down(o3, off);
    }
    if (lane == 0) {
      float4 o = { o0 + c0, o1 + c1, o2 + c2, o3 + c3 };
      *reinterpret_cast<float4*>(out + (size_t)b * 4) = o;
    }
  }
}

// ---------------- launch ----------------
extern "C" void kernel_launch(void* const* d_in, const int* in_sizes, int n_in,
                              void* d_out, int out_size, void* d_ws, size_t ws_size,
                              hipStream_t stream) {
  const float* userF = (const float*)d_in[0];
  const float* itemF = (const float*)d_in[1];
  const int*   src   = (const int*)d_in[2];
  const int*   dst   = src + NE;
  const int*   eliU  = (const int*)d_in[3];
  const int*   eliI  = eliU + NB;
  const float* upW = (const float*)d_in[4],  *upb = (const float*)d_in[5];
  const float* ipW = (const float*)d_in[6],  *ipb = (const float*)d_in[7];
  const float* ulW = (const float*)d_in[8],  *ulb = (const float*)d_in[9];
  const float* urW = (const float*)d_in[10];
  const float* ilW = (const float*)d_in[11], *ilb = (const float*)d_in[12];
  const float* irW = (const float*)d_in[13];
  const float* ug  = (const float*)d_in[14], *ube = (const float*)d_in[15];
  const float* um  = (const float*)d_in[16], *uv  = (const float*)d_in[17];
  const float* ig  = (const float*)d_in[18], *ibe = (const float*)d_in[19];
  const float* im  = (const float*)d_in[20], *iv  = (const float*)d_in[21];
  const float* f1W = (const float*)d_in[22], *f1b = (const float*)d_in[23];
  const float* f2W = (const float*)d_in[24], *f2b = (const float*)d_in[25];
  float* outp = (float*)d_out;

  char* p = (char*)d_ws;
  auto alloc = [&](size_t bytes) {
    char* r = p;
    p += (bytes + 255) & ~(size_t)255;
    return r;
  };
  float* ux0  = (float*)alloc((size_t)N_USERS * H * 4);
  float* ux1  = (float*)alloc((size_t)N_USERS * H * 4);
  float* ix0  = (float*)alloc((size_t)N_ITEMS * H * 4);
  float* ix1  = (float*)alloc((size_t)N_ITEMS * H * 4);
  float* agU  = (float*)alloc((size_t)N_USERS * H * 4);
  float* agI  = (float*)alloc((size_t)N_ITEMS * H * 4);
  int*   rowU = (int*)alloc((size_t)(N_USERS + 1) * 4);
  int*   rowI = (int*)alloc((size_t)(N_ITEMS + 1) * 4);
  int*   curU = (int*)alloc((size_t)N_USERS * 4);
  int*   curI = (int*)alloc((size_t)N_ITEMS * 4);
  int*   cntUI = (int*)alloc((size_t)(N_USERS + N_ITEMS) * 4);
  int*   cntU = cntUI;
  int*   cntI = cntUI + N_USERS;
  int*   adjU = (int*)alloc((size_t)NE * 4);
  int*   adjI = (int*)alloc((size_t)NE * 4);

  hipMemsetAsync(cntUI, 0, (size_t)(N_USERS + N_ITEMS) * 4, stream);

  const int G = 2048, T = 256;
  proj_kernel<256><<<G, T, 0, stream>>>(userF, upW, upb, ux0, N_USERS);
  proj_kernel<128><<<G, T, 0, stream>>>(itemF, ipW, ipb, ix0, N_ITEMS);
  hist_kernel<<<G, T, 0, stream>>>(src, dst, cntU, cntI);
  scan_kernel<<<1, 1024, 0, stream>>>(cntU, rowU, curU, N_USERS);
  scan_kernel<<<1, 1024, 0, stream>>>(cntI, rowI, curI, N_ITEMS);
  scatter_kernel<<<G, T, 0, stream>>>(src, dst, curU, curI, adjU, adjI);

  const float* uin = ux0;
  const float* iin = ix0;
  float* uout = ux1;
  float* iout = ix1;
  for (int l = 0; l < 2; l++) {
    agg_max_kernel<<<G, T, 0, stream>>>(iin, rowU, adjU, agU, N_USERS);
    conv_kernel<<<G, T, 0, stream>>>(agU, uin, ulW + l * 4096, ulb + l * 64,
                                     urW + l * 4096, ug + l * 64, ube + l * 64,
                                     um + l * 64, uv + l * 64, uout, N_USERS);
    agg_mean_kernel<<<G, T, 0, stream>>>(uin, rowI, adjI, agI, N_ITEMS);
    conv_kernel<<<G, T, 0, stream>>>(agI, iin, ilW + l * 4096, ilb + l * 64,
                                     irW + l * 4096, ig + l * 64, ibe + l * 64,
                                     im + l * 64, iv + l * 64, iout, N_ITEMS);
    const float* t;
    t = uin; uin = uout; uout = (float*)t;
    t = iin; iin = iout; iout = (float*)t;
  }
  head_kernel<<<G, T, 0, stream>>>(uin, iin, eliU, eliI, f1W, f1b, f2W, f2b, outp);
}

// Round 3
// 1035.271 us; speedup vs baseline: 1.2943x; 1.1046x over previous
//
#include <hip/hip_runtime.h>
#include <math.h>

#define N_USERS 100000
#define N_ITEMS 50000
#define NE      2000000
#define NB      100000
#define H       64
#define BN_EPS  1e-5f
#define NXCD    8
#define U_LOC   (N_USERS / NXCD)          // 12500 users per partition
#define I_LOC   (N_ITEMS / NXCD)          // 6250 items per partition
#define HSLOTS  (U_LOC + I_LOC)           // 18750 ints = 75 KB LDS
#define S_SLICES 64                        // edge slices per partition
#define NBLK_CSR (NXCD * S_SLICES)         // 512 blocks
#define E_SLICE  (NE / S_SLICES)           // 31250 edges per slice

static __device__ __forceinline__ int rfl(int x) { return __builtin_amdgcn_readfirstlane(x); }

// ---------------- projection: Y[N,64] = X[N,K] @ W[K,64] + b ----------------
template<int K>
__global__ __launch_bounds__(256) void proj_kernel(
    const float* __restrict__ X, const float* __restrict__ W,
    const float* __restrict__ bias, float* __restrict__ Y, int nrows) {
  constexpr int SL = K / 4;
  const int lane = threadIdx.x & 63;
  const int wid  = rfl((int)(threadIdx.x >> 6));
  const int k0   = wid * SL;
  float w[SL];
#pragma unroll
  for (int k = 0; k < SL; k++) w[k] = W[(k0 + k) * H + lane];
  const float bv = bias[lane];
  __shared__ float part[4][64];
  for (int r = blockIdx.x; r < nrows; r += gridDim.x) {
    const float* xr = X + (size_t)r * K + k0;
    float acc = 0.f;
#pragma unroll
    for (int k = 0; k < SL; k++) acc = fmaf(xr[k], w[k], acc);
    part[wid][lane] = acc;
    __syncthreads();
    if (wid == 0) {
      Y[(size_t)r * H + lane] =
          part[0][lane] + part[1][lane] + part[2][lane] + part[3][lane] + bv;
    }
    __syncthreads();
  }
}

// ---------------- CSR build, atomic-free counting sort ----------------
// Block b = (x = b&7 [XCD/partition], s = b>>3 [edge slice]).
// Phase 1: private LDS histogram of owned nodes over slice s -> PH[b][*].
__global__ __launch_bounds__(256) void hist2_kernel(
    const int* __restrict__ src, const int* __restrict__ dst,
    int* __restrict__ PH) {
  __shared__ int h[HSLOTS];
  const int x = blockIdx.x & (NXCD - 1);
  const int s = blockIdx.x >> 3;
  for (int i = threadIdx.x; i < HSLOTS; i += 256) h[i] = 0;
  __syncthreads();
  const int uLo = x * U_LOC, iLo = x * I_LOC;
  const int e0 = s * E_SLICE;
  for (int e = e0 + threadIdx.x; e < e0 + E_SLICE; e += 256) {
    const int u  = __builtin_nontemporal_load(&src[e]);
    const int it = __builtin_nontemporal_load(&dst[e]);
    const int ul = u - uLo, il = it - iLo;
    if ((unsigned)ul < (unsigned)U_LOC) atomicAdd(&h[ul], 1);
    if ((unsigned)il < (unsigned)I_LOC) atomicAdd(&h[U_LOC + il], 1);
  }
  __syncthreads();
  int* out = PH + (size_t)blockIdx.x * HSLOTS;
  for (int i = threadIdx.x; i < HSLOTS; i += 256) out[i] = h[i];
}

// Phase 2: per (partition, node): exclusive prefix over the 64 slices
// (in place) + total count. All accesses coalesced across threads.
__global__ __launch_bounds__(256) void combine_kernel(
    int* __restrict__ PH, int* __restrict__ cntU, int* __restrict__ cntI) {
  const int g = blockIdx.x * 256 + threadIdx.x;
  if (g >= NXCD * HSLOTS) return;
  const int x = g / HSLOTS;
  const int n = g - x * HSLOTS;
  int* p = PH + (size_t)x * HSLOTS + n;
  int run = 0;
#pragma unroll 4
  for (int s = 0; s < S_SLICES; s++) {
    int* q = p + (size_t)s * (NXCD * HSLOTS);
    const int v = *q;
    *q = run;
    run += v;
  }
  if (n < U_LOC) cntU[x * U_LOC + n] = run;
  else           cntI[x * I_LOC + (n - U_LOC)] = run;
}

// single-block exclusive scan: 8 elems/thread, wave shfl-scan + LDS combine
__global__ __launch_bounds__(1024) void scan_kernel(
    const int* __restrict__ cnt, int* __restrict__ row, int n) {
  __shared__ int wtot[16];
  __shared__ int carry_s;
  const int tid = threadIdx.x;
  const int lane = tid & 63, wv = tid >> 6;
  if (tid == 0) { carry_s = 0; row[0] = 0; }
  __syncthreads();
  for (int base = 0; base < n; base += 8192) {
    const int i0 = base + tid * 8;
    int v, sacc[8];
    int run = 0;
#pragma unroll
    for (int k = 0; k < 8; k++) {
      v = (i0 + k < n) ? cnt[i0 + k] : 0;
      run += v;
      sacc[k] = run;
    }
    int x = run;
#pragma unroll
    for (int off = 1; off < 64; off <<= 1) {
      const int y = __shfl_up(x, off);
      if (lane >= off) x += y;
    }
    if (lane == 63) wtot[wv] = x;
    __syncthreads();
    int woff = 0;
#pragma unroll
    for (int k = 0; k < 16; k++) woff += (k < wv) ? wtot[k] : 0;
    const int thr_excl = (x - run) + woff + carry_s;
#pragma unroll
    for (int k = 0; k < 8; k++)
      if (i0 + k < n) row[i0 + k + 1] = thr_excl + sacc[k];
    __syncthreads();
    if (tid == 1023) carry_s = thr_excl + run;
    __syncthreads();
  }
}

// Phase 3: deterministic scatter. pos[n] = rowptr[n] + slice-prefix; LDS
// fetch-add gives each edge its slot. No global atomics anywhere.
__global__ __launch_bounds__(256) void scatter2_kernel(
    const int* __restrict__ src, const int* __restrict__ dst,
    const int* __restrict__ PH, const int* __restrict__ rowU,
    const int* __restrict__ rowI, int* __restrict__ adjU,
    int* __restrict__ adjI) {
  __shared__ int pos[HSLOTS];
  const int x = blockIdx.x & (NXCD - 1);
  const int s = blockIdx.x >> 3;
  const int uLo = x * U_LOC, iLo = x * I_LOC;
  const int* pre = PH + (size_t)blockIdx.x * HSLOTS;
  for (int i = threadIdx.x; i < U_LOC; i += 256)
    pos[i] = rowU[uLo + i] + pre[i];
  for (int i = threadIdx.x; i < I_LOC; i += 256)
    pos[U_LOC + i] = rowI[iLo + i] + pre[U_LOC + i];
  __syncthreads();
  const int e0 = s * E_SLICE;
  for (int e = e0 + threadIdx.x; e < e0 + E_SLICE; e += 256) {
    const int u  = __builtin_nontemporal_load(&src[e]);
    const int it = __builtin_nontemporal_load(&dst[e]);
    const int ul = u - uLo, il = it - iLo;
    if ((unsigned)ul < (unsigned)U_LOC) {
      const int p = atomicAdd(&pos[ul], 1);
      adjU[p] = it;
    }
    if ((unsigned)il < (unsigned)I_LOC) {
      const int p = atomicAdd(&pos[U_LOC + il], 1);
      adjI[p] = u;
    }
  }
}

// ---------------- aggregations: one wave per segment, lane = channel ----------------
__global__ __launch_bounds__(256) void agg_max_kernel(
    const float* __restrict__ feat, const int* __restrict__ rowptr,
    const int* __restrict__ adj, float* __restrict__ out, int nseg) {
  const int lane = threadIdx.x & 63;
  const int wid  = rfl((int)(threadIdx.x >> 6));
  for (int s = blockIdx.x * 4 + wid; s < nseg; s += gridDim.x * 4) {
    const int beg = rowptr[s], end = rowptr[s + 1];
    float m0 = -INFINITY, m1 = -INFINITY, m2 = -INFINITY, m3 = -INFINITY;
    int j = beg;
    for (; j + 4 <= end; j += 4) {
      const int n0 = adj[j], n1 = adj[j + 1], n2 = adj[j + 2], n3 = adj[j + 3];
      m0 = fmaxf(m0, feat[(size_t)n0 * H + lane]);
      m1 = fmaxf(m1, feat[(size_t)n1 * H + lane]);
      m2 = fmaxf(m2, feat[(size_t)n2 * H + lane]);
      m3 = fmaxf(m3, feat[(size_t)n3 * H + lane]);
    }
    for (; j < end; j++) m0 = fmaxf(m0, feat[(size_t)adj[j] * H + lane]);
    const float m = fmaxf(fmaxf(m0, m1), fmaxf(m2, m3));
    out[(size_t)s * H + lane] = (end > beg) ? m : 0.f;  // empty segment -> 0 (PyG)
  }
}

__global__ __launch_bounds__(256) void agg_mean_kernel(
    const float* __restrict__ feat, const int* __restrict__ rowptr,
    const int* __restrict__ adj, float* __restrict__ out, int nseg) {
  const int lane = threadIdx.x & 63;
  const int wid  = rfl((int)(threadIdx.x >> 6));
  for (int s = blockIdx.x * 4 + wid; s < nseg; s += gridDim.x * 4) {
    const int beg = rowptr[s], end = rowptr[s + 1];
    float a0 = 0.f, a1 = 0.f, a2 = 0.f, a3 = 0.f;
    int j = beg;
    for (; j + 4 <= end; j += 4) {
      const int n0 = adj[j], n1 = adj[j + 1], n2 = adj[j + 2], n3 = adj[j + 3];
      a0 += feat[(size_t)n0 * H + lane];
      a1 += feat[(size_t)n1 * H + lane];
      a2 += feat[(size_t)n2 * H + lane];
      a3 += feat[(size_t)n3 * H + lane];
    }
    for (; j < end; j++) a0 += feat[(size_t)adj[j] * H + lane];
    const float inv = 1.f / (float)((end - beg) > 1 ? (end - beg) : 1);
    out[(size_t)s * H + lane] = ((a0 + a1) + (a2 + a3)) * inv;
  }
}

// ---------------- fused conv: Y = relu(BN(AGG@Wl + bl + XS@Wr)) ----------------
__global__ __launch_bounds__(256) void conv_kernel(
    const float* __restrict__ AGG, const float* __restrict__ XS,
    const float* __restrict__ Wl, const float* __restrict__ bl,
    const float* __restrict__ Wr, const float* __restrict__ gm,
    const float* __restrict__ bt, const float* __restrict__ mu,
    const float* __restrict__ vr, float* __restrict__ Y, int nrows) {
  const int lane = threadIdx.x & 63;
  const int wid  = rfl((int)(threadIdx.x >> 6));
  float wl[64], wr[64];
#pragma unroll
  for (int k = 0; k < 64; k++) wl[k] = Wl[k * 64 + lane];
#pragma unroll
  for (int k = 0; k < 64; k++) wr[k] = Wr[k * 64 + lane];
  const float s = gm[lane] * rsqrtf(vr[lane] + BN_EPS);
  const float C = (bl[lane] - mu[lane]) * s + bt[lane];
  for (int r = blockIdx.x * 4 + wid; r < nrows; r += gridDim.x * 4) {
    const float* a = AGG + (size_t)r * 64;
    const float* x = XS + (size_t)r * 64;
    float acc = 0.f;
#pragma unroll
    for (int k = 0; k < 64; k++) acc = fmaf(a[k], wl[k], acc);
#pragma unroll
    for (int k = 0; k < 64; k++) acc = fmaf(x[k], wr[k], acc);
    Y[(size_t)r * 64 + lane] = fmaxf(fmaf(acc, s, C), 0.f);
  }
}

// ---------------- head ----------------
__global__ __launch_bounds__(256) void head_kernel(
    const float* __restrict__ ux, const float* __restrict__ ix,
    const int* __restrict__ eliU, const int* __restrict__ eliI,
    const float* __restrict__ W1, const float* __restrict__ b1,
    const float* __restrict__ W2, const float* __restrict__ b2,
    float* __restrict__ out) {
  const int lane = threadIdx.x & 63;
  const int wid  = rfl((int)(threadIdx.x >> 6));
  float w1[128];
#pragma unroll
  for (int k = 0; k < 128; k++) w1[k] = W1[k * 64 + lane];
  const float b1v = b1[lane];
  const float w2a = W2[lane * 4 + 0], w2b = W2[lane * 4 + 1];
  const float w2c = W2[lane * 4 + 2], w2d = W2[lane * 4 + 3];
  const float c0 = b2[0], c1 = b2[1], c2 = b2[2], c3 = b2[3];
  for (int b = blockIdx.x * 4 + wid; b < NB; b += gridDim.x * 4) {
    const int u = eliU[b], it = eliI[b];
    const float* xu = ux + (size_t)u * 64;
    const float* xi = ix + (size_t)it * 64;
    float acc = b1v;
#pragma unroll
    for (int k = 0; k < 64; k++) acc = fmaf(xu[k], w1[k], acc);
#pragma unroll
    for (int k = 0; k < 64; k++) acc = fmaf(xi[k], w1[64 + k], acc);
    const float h = fmaxf(acc, 0.f);
    float o0 = h * w2a, o1 = h * w2b, o2 = h * w2c, o3 = h * w2d;
#pragma unroll
    for (int off = 32; off; off >>= 1) {
      o0 += __shfl_down(o0, off);
      o1 += __shfl_down(o1, off);
      o2 += __shfl_down(o2, off);
      o3 += __shfl_down(o3, off);
    }
    if (lane == 0) {
      float4 o = { o0 + c0, o1 + c1, o2 + c2, o3 + c3 };
      *reinterpret_cast<float4*>(out + (size_t)b * 4) = o;
    }
  }
}

// ---------------- launch ----------------
extern "C" void kernel_launch(void* const* d_in, const int* in_sizes, int n_in,
                              void* d_out, int out_size, void* d_ws, size_t ws_size,
                              hipStream_t stream) {
  const float* userF = (const float*)d_in[0];
  const float* itemF = (const float*)d_in[1];
  const int*   src   = (const int*)d_in[2];
  const int*   dst   = src + NE;
  const int*   eliU  = (const int*)d_in[3];
  const int*   eliI  = eliU + NB;
  const float* upW = (const float*)d_in[4],  *upb = (const float*)d_in[5];
  const float* ipW = (const float*)d_in[6],  *ipb = (const float*)d_in[7];
  const float* ulW = (const float*)d_in[8],  *ulb = (const float*)d_in[9];
  const float* urW = (const float*)d_in[10];
  const float* ilW = (const float*)d_in[11], *ilb = (const float*)d_in[12];
  const float* irW = (const float*)d_in[13];
  const float* ug  = (const float*)d_in[14], *ube = (const float*)d_in[15];
  const float* um  = (const float*)d_in[16], *uv  = (const float*)d_in[17];
  const float* ig  = (const float*)d_in[18], *ibe = (const float*)d_in[19];
  const float* im  = (const float*)d_in[20], *iv  = (const float*)d_in[21];
  const float* f1W = (const float*)d_in[22], *f1b = (const float*)d_in[23];
  const float* f2W = (const float*)d_in[24], *f2b = (const float*)d_in[25];
  float* outp = (float*)d_out;

  char* p = (char*)d_ws;
  auto alloc = [&](size_t bytes) {
    char* r = p;
    p += (bytes + 255) & ~(size_t)255;
    return r;
  };
  float* ux0  = (float*)alloc((size_t)N_USERS * H * 4);
  float* ux1  = (float*)alloc((size_t)N_USERS * H * 4);
  float* ix0  = (float*)alloc((size_t)N_ITEMS * H * 4);
  float* ix1  = (float*)alloc((size_t)N_ITEMS * H * 4);
  float* agU  = (float*)alloc((size_t)N_USERS * H * 4);   // 25.6 MB
  float* agI  = (float*)alloc((size_t)N_ITEMS * H * 4);   // 12.8 MB (contiguous after agU)
  int*   rowU = (int*)alloc((size_t)(N_USERS + 1) * 4);
  int*   rowI = (int*)alloc((size_t)(N_ITEMS + 1) * 4);
  int*   cntU = (int*)alloc((size_t)N_USERS * 4);
  int*   cntI = (int*)alloc((size_t)N_ITEMS * 4);
  int*   adjU = (int*)alloc((size_t)NE * 4);
  int*   adjI = (int*)alloc((size_t)NE * 4);
  // PH (512 blocks x 18750 ints = 38.4 MB) aliases agU+agI: dead before the
  // aggregation phase first writes agU/agI.
  int*   PH   = (int*)agU;

  const int G = 2048, T = 256;
  proj_kernel<256><<<G, T, 0, stream>>>(userF, upW, upb, ux0, N_USERS);
  proj_kernel<128><<<G, T, 0, stream>>>(itemF, ipW, ipb, ix0, N_ITEMS);
  hist2_kernel<<<NBLK_CSR, T, 0, stream>>>(src, dst, PH);
  combine_kernel<<<(NXCD * HSLOTS + 255) / 256, T, 0, stream>>>(PH, cntU, cntI);
  scan_kernel<<<1, 1024, 0, stream>>>(cntU, rowU, N_USERS);
  scan_kernel<<<1, 1024, 0, stream>>>(cntI, rowI, N_ITEMS);
  scatter2_kernel<<<NBLK_CSR, T, 0, stream>>>(src, dst, PH, rowU, rowI, adjU, adjI);

  const float* uin = ux0;
  const float* iin = ix0;
  float* uout = ux1;
  float* iout = ix1;
  for (int l = 0; l < 2; l++) {
    agg_max_kernel<<<G, T, 0, stream>>>(iin, rowU, adjU, agU, N_USERS);
    conv_kernel<<<G, T, 0, stream>>>(agU, uin, ulW + l * 4096, ulb + l * 64,
                                     urW + l * 4096, ug + l * 64, ube + l * 64,
                                     um + l * 64, uv + l * 64, uout, N_USERS);
    agg_mean_kernel<<<G, T, 0, stream>>>(uin, rowI, adjI, agI, N_ITEMS);
    conv_kernel<<<G, T, 0, stream>>>(agI, iin, ilW + l * 4096, ilb + l * 64,
                                     irW + l * 4096, ig + l * 64, ibe + l * 64,
                                     im + l * 64, iv + l * 64, iout, N_ITEMS);
    const float* t;
    t = uin; uin = uout; uout = (float*)t;
    t = iin; iin = iout; iout = (float*)t;
  }
  head_kernel<<<G, T, 0, stream>>>(uin, iin, eliU, eliI, f1W, f1b, f2W, f2b, outp);
}